// Round 3
// baseline (238.495 us; speedup 1.0000x reference)
//
#include <hip/hip_runtime.h>
#include <hip/hip_fp16.h>

typedef _Float16 f16;
typedef _Float16 f16x8 __attribute__((ext_vector_type(8)));
typedef _Float16 f16x4 __attribute__((ext_vector_type(4)));
typedef float f32x4 __attribute__((ext_vector_type(4)));

#define NSZ 256
#define NIMG 384

// Swizzled LDS index (halves): row r, half-col c; XOR 16B granule by row&7.
__device__ __forceinline__ int sw(int r, int c) {
  return r * NSZ + (c ^ ((r & 7) << 3));
}

// Tables: Cm[k][h] = C[k,h], CTm[h][k] = C[k,h]; g[b][n]; Kq[b] = roundup64(#rows kept).
__global__ void prep_kernel(f16* __restrict__ Cm, f16* __restrict__ CTm,
                            float* __restrict__ g, int* __restrict__ Kq,
                            const float* __restrict__ t) {
  int k = blockIdx.x;
  int h = threadIdx.x;
  double scale = (k == 0) ? 0.0625 : 0.08838834764831844;  // sqrt(1/256), sqrt(2/256)
  double val = cos(3.14159265358979323846 * ((double)h + 0.5) * (double)k / 256.0) * scale;
  f16 vh = (f16)((float)val);
  Cm[k * NSZ + h] = vh;
  CTm[h * NSZ + k] = vh;
  int pred = 0;
  if (k < 128) {
    float tb = t[k];
    float sg = expf(-0.69314718055994531f * (1.0f - tb) + 2.99573227355399099f * tb);
    float tau = 0.5f * sg * sg;
    float f = 3.14159265358979f * (float)h / 256.0f;
    float gv = expf(-f * f * tau);
    g[k * NSZ + h] = gv;
    pred = (gv >= 0.0099f) ? 1 : 0;  // conservative row-keep (cell mask is exact)
  }
  int cnt = __syncthreads_count(pred);
  if (k < 128 && h == 0) {
    int K = ((cnt + 63) >> 6) << 6;
    if (K < 64) K = 64;
    if (K > 256) K = 256;
    Kq[k] = K;
  }
}

// Kernel A: per (img, nb): E''[k<Kq][nb band] = 0.999*fade'(k,n) * (C X C^T)[k,n]
// P1t[n][h] = sum_w X[h,w] C[n,w]  (D[h][n] via MFMA NT, transposed store)
// E[k][n]   = sum_h C[k,h] P1t[n,h]
__global__ __launch_bounds__(512, 4) void kernelA(
    const float* __restrict__ x, f16* __restrict__ Ep,
    const f16* __restrict__ Cm, const float* __restrict__ g,
    const int* __restrict__ Kq_arr) {
  __shared__ char smem[69632];
  f16* P1 = (f16*)smem;            // 32KB [n64][h256] swizzled
  f16* Xs = (f16*)(smem + 32768);  // 32KB [h64][w256] swizzled; reused as Estage stride 72

  int bid0 = blockIdx.x;
  int bid = (bid0 & 7) * 192 + (bid0 >> 3);  // XCD-chunked swizzle (1536 = 8*192)
  int img = bid >> 2, nb = bid & 3;
  int b = img / 3;
  int Kq = Kq_arr[b];
  if (nb * 64 >= Kq) return;

  int t = threadIdx.x, lane = t & 63, wave = t >> 6;
  int lrow = lane & 15, lk = (lane >> 4) * 8, lv4 = (lane >> 4) * 4;
  const float* X = x + (size_t)img * 65536;

  // ---- Phase 1: build P1t[n_loc 64][h 256]
  int hi = wave >> 1, ni = wave & 1;
  for (int hc = 0; hc < 4; ++hc) {
    if (hc) __syncthreads();
#pragma unroll
    for (int c = 0; c < 4; ++c) {
      int gid = t + c * 512;
      int r = gid >> 5, c8 = (gid & 31) << 3;
      const float* s = X + (hc * 64 + r) * NSZ + c8;
      float4 a0 = *(const float4*)s;
      float4 a1 = *(const float4*)(s + 4);
      f16x8 v;
      v[0] = (f16)a0.x; v[1] = (f16)a0.y; v[2] = (f16)a0.z; v[3] = (f16)a0.w;
      v[4] = (f16)a1.x; v[5] = (f16)a1.y; v[6] = (f16)a1.z; v[7] = (f16)a1.w;
      *(f16x8*)&Xs[sw(r, c8)] = v;
    }
    __syncthreads();
    f32x4 accP[2];
#pragma unroll
    for (int j = 0; j < 2; ++j) { f32x4 z = {0.f, 0.f, 0.f, 0.f}; accP[j] = z; }
    for (int ks = 0; ks < 8; ++ks) {
      int kh = ks * 32 + lk;
      f16x8 o1 = *(const f16x8*)&Xs[sw(hi * 16 + lrow, kh)];
#pragma unroll
      for (int j = 0; j < 2; ++j) {
        int n = nb * 64 + ni * 32 + j * 16 + lrow;
        f16x8 o2 = *(const f16x8*)&Cm[n * NSZ + kh];
        accP[j] = __builtin_amdgcn_mfma_f32_16x16x32_f16(o1, o2, accP[j], 0, 0, 0);
      }
    }
    // transposed store D[h][n] -> P1[n_loc][h]
#pragma unroll
    for (int j = 0; j < 2; ++j) {
      int n_loc = ni * 32 + j * 16 + lrow;
      int hp = hc * 64 + hi * 16 + lv4;
      f16x4 hv;
      hv[0] = (f16)accP[j][0]; hv[1] = (f16)accP[j][1];
      hv[2] = (f16)accP[j][2]; hv[3] = (f16)accP[j][3];
      *(f16x4*)&P1[sw(n_loc, hp)] = hv;
    }
  }
  __syncthreads();

  // ---- Phase 2: E[k][n] for wave's 32-row k band
  f16* Est = (f16*)Xs;  // stride 72 halves
  int kb0 = wave * 32;
  if (kb0 < Kq) {
    f32x4 accE[2][4];
#pragma unroll
    for (int i = 0; i < 2; ++i)
#pragma unroll
      for (int j = 0; j < 4; ++j) { f32x4 z = {0.f, 0.f, 0.f, 0.f}; accE[i][j] = z; }
    for (int ks = 0; ks < 8; ++ks) {
      int kh = ks * 32 + lk;
      f16x8 o1[2], o2[4];
#pragma unroll
      for (int i = 0; i < 2; ++i)
        o1[i] = *(const f16x8*)&Cm[(kb0 + i * 16 + lrow) * NSZ + kh];
#pragma unroll
      for (int j = 0; j < 4; ++j)
        o2[j] = *(const f16x8*)&P1[sw(j * 16 + lrow, kh)];
#pragma unroll
      for (int i = 0; i < 2; ++i)
#pragma unroll
        for (int j = 0; j < 4; ++j)
          accE[i][j] = __builtin_amdgcn_mfma_f32_16x16x32_f16(o1[i], o2[j], accE[i][j], 0, 0, 0);
    }
    const float* gb = g + b * NSZ;
#pragma unroll
    for (int i = 0; i < 2; ++i) {
#pragma unroll
      for (int j = 0; j < 4; ++j) {
        float gn = gb[nb * 64 + j * 16 + lrow];
#pragma unroll
        for (int v = 0; v < 4; ++v) {
          int k = kb0 + i * 16 + lv4 + v;
          float fade = gb[k] * gn;
          float s = (fade < 0.01f) ? 0.f : 0.999f * fade;
          Est[k * 72 + j * 16 + lrow] = (f16)(accE[i][j][v] * s);
        }
      }
    }
  }
  __syncthreads();
  // coalesced copy-out rows k < Kq
  f16* Eout = Ep + (size_t)img * 65536 + nb * 64;
  for (int gg = t; gg < Kq * 8; gg += 512) {
    int k = gg >> 3, gn = gg & 7;
    f16x8 v = *(const f16x8*)&Est[k * 72 + gn * 8];
    *(f16x8*)&Eout[k * NSZ + gn * 8] = v;
  }
}

// Kernel B: per (img, wb): Y[h][wb band] = 0.001*X + sum_k C[k,h] * Q[k,w],
// Q[k,w] = sum_n E''[k,n] C[n,w].  Qt[w][k] built per 64-k chunk, then one Y-GEMM.
__global__ __launch_bounds__(512, 4) void kernelB(
    const float* __restrict__ x, const f16* __restrict__ Ep,
    float* __restrict__ out, const f16* __restrict__ CTm,
    const int* __restrict__ Kq_arr) {
  __shared__ char smem[69632];
  f16* Ech = (f16*)smem;            // 32KB [k64][n256] swizzled
  f16* Qt = (f16*)(smem + 32768);   // 32KB [w64][k256] swizzled
  float* Yt = (float*)smem;         // [h256][68] fp32 (aliases Ech+Qt after final sync)

  int bid0 = blockIdx.x;
  int bid = (bid0 & 7) * 192 + (bid0 >> 3);
  int img = bid >> 2, wb = bid & 3;
  int b = img / 3;
  int Kq = Kq_arr[b];
  int nks = Kq >> 5, nkc = Kq >> 6;

  int t = threadIdx.x, lane = t & 63, wave = t >> 6;
  int lrow = lane & 15, lk = (lane >> 4) * 8, lv4 = (lane >> 4) * 4;
  const float* X = x + (size_t)img * 65536;

  // ---- Phase 1: Qt[w_loc][k<Kq]
  int ki = wave >> 1, wj = wave & 1;
  for (int kc = 0; kc < nkc; ++kc) {
    __syncthreads();
    {
      int k = t >> 3, sub = t & 7;
      int gpr = Kq >> 3;
      const f16* src = Ep + (size_t)img * 65536 + (kc * 64 + k) * NSZ;
      for (int gg = sub; gg < gpr; gg += 8) {
        f16x8 v = *(const f16x8*)&src[gg * 8];
        *(f16x8*)&Ech[sw(k, gg * 8)] = v;
      }
    }
    __syncthreads();
    f32x4 accQ[2];
#pragma unroll
    for (int j = 0; j < 2; ++j) { f32x4 z = {0.f, 0.f, 0.f, 0.f}; accQ[j] = z; }
    for (int ks = 0; ks < nks; ++ks) {
      int kh = ks * 32 + lk;
      f16x8 o1 = *(const f16x8*)&Ech[sw(ki * 16 + lrow, kh)];
#pragma unroll
      for (int j = 0; j < 2; ++j) {
        int w = wb * 64 + wj * 32 + j * 16 + lrow;
        f16x8 o2 = *(const f16x8*)&CTm[w * NSZ + kh];
        accQ[j] = __builtin_amdgcn_mfma_f32_16x16x32_f16(o1, o2, accQ[j], 0, 0, 0);
      }
    }
#pragma unroll
    for (int j = 0; j < 2; ++j) {
      int w_loc = wj * 32 + j * 16 + lrow;
      int kp = kc * 64 + ki * 16 + lv4;
      f16x4 hv;
      hv[0] = (f16)accQ[j][0]; hv[1] = (f16)accQ[j][1];
      hv[2] = (f16)accQ[j][2]; hv[3] = (f16)accQ[j][3];
      *(f16x4*)&Qt[sw(w_loc, kp)] = hv;
    }
  }
  __syncthreads();

  // ---- Phase 2: Y[h band 32][w 64] = sum_{k<Kq} CTm[h,k] Qt[w,k]
  f32x4 accY[2][4];
#pragma unroll
  for (int i = 0; i < 2; ++i)
#pragma unroll
    for (int j = 0; j < 4; ++j) { f32x4 z = {0.f, 0.f, 0.f, 0.f}; accY[i][j] = z; }
  for (int ks = 0; ks < nks; ++ks) {
    int kh = ks * 32 + lk;
    f16x8 o1[2], o2[4];
#pragma unroll
    for (int i = 0; i < 2; ++i)
      o1[i] = *(const f16x8*)&CTm[(wave * 32 + i * 16 + lrow) * NSZ + kh];
#pragma unroll
    for (int j = 0; j < 4; ++j)
      o2[j] = *(const f16x8*)&Qt[sw(j * 16 + lrow, kh)];
#pragma unroll
    for (int i = 0; i < 2; ++i)
#pragma unroll
      for (int j = 0; j < 4; ++j)
        accY[i][j] = __builtin_amdgcn_mfma_f32_16x16x32_f16(o1[i], o2[j], accY[i][j], 0, 0, 0);
  }
  __syncthreads();  // all waves done reading Qt before Yt aliases it
#pragma unroll
  for (int i = 0; i < 2; ++i)
#pragma unroll
    for (int j = 0; j < 4; ++j)
#pragma unroll
      for (int v = 0; v < 4; ++v)
        Yt[(wave * 32 + i * 16 + lv4 + v) * 68 + j * 16 + lrow] = accY[i][j][v];
  __syncthreads();
  // coalesced copy-out + exact 0.001*X term
  float* Yo = out + (size_t)img * 65536 + wb * 64;
#pragma unroll
  for (int it = 0; it < 8; ++it) {
    int idx = it * 512 + t;
    int row = idx >> 4, q = (idx & 15) * 4;
    float4 yv = *(const float4*)&Yt[row * 68 + q];
    float4 xv = *(const float4*)&X[row * NSZ + wb * 64 + q];
    yv.x += 0.001f * xv.x; yv.y += 0.001f * xv.y;
    yv.z += 0.001f * xv.z; yv.w += 0.001f * xv.w;
    *(float4*)&Yo[row * NSZ + q] = yv;
  }
}

extern "C" void kernel_launch(void* const* d_in, const int* in_sizes, int n_in,
                              void* d_out, int out_size, void* d_ws, size_t ws_size,
                              hipStream_t stream) {
  const float* x = (const float*)d_in[0];
  const float* t = (const float*)d_in[1];
  float* out = (float*)d_out;

  char* ws = (char*)d_ws;
  float* g = (float*)ws;            // 131072 B
  f16* Cm = (f16*)(ws + 131072);    // 131072 B
  f16* CTm = (f16*)(ws + 262144);   // 131072 B
  int* Kq = (int*)(ws + 393216);    // 512 B
  f16* Ep = (f16*)(ws + 393728);    // 384*65536*2 = 50331648 B

  prep_kernel<<<256, 256, 0, stream>>>(Cm, CTm, g, Kq, t);
  kernelA<<<NIMG * 4, 512, 0, stream>>>(x, Ep, Cm, g, Kq);
  kernelB<<<NIMG * 4, 512, 0, stream>>>(x, Ep, out, CTm, Kq);
}

// Round 4
// 99.387 us; speedup vs baseline: 2.3997x; 2.3997x over previous
//
#include <hip/hip_runtime.h>
#include <hip/hip_fp16.h>

typedef _Float16 f16;
typedef _Float16 f16x8 __attribute__((ext_vector_type(8)));
typedef _Float16 f16x4 __attribute__((ext_vector_type(4)));
typedef float f32x16 __attribute__((ext_vector_type(16)));

#define NSZ 256
#define NIMG 384

// Swizzled LDS index (halves): row r, half-col c; XOR 16B granule by r&15.
__device__ __forceinline__ int sw(int r, int c) {
  return r * NSZ + (c ^ ((r & 15) << 3));
}

// Fragment-layout offset for tables: element (row r, col c) ->
// [tile=r>>5][chunk=c>>4][lane=((c>>3)&1)*32+(r&31)][j=c&7]
__device__ __forceinline__ int frag_off(int r, int c) {
  return (((((r >> 5) * 16 + (c >> 4)) << 6) + (((c >> 3) & 1) << 5) + (r & 31)) << 3) + (c & 7);
}

// Tables: Cf = frag(C[k][h]), CTf = frag(C^T[h][k]); g[b][i] = exp(-f_i^2 tau_b).
__global__ void prep_kernel(f16* __restrict__ Cf, f16* __restrict__ CTf,
                            float* __restrict__ g, const float* __restrict__ t) {
  int k = blockIdx.x;
  int h = threadIdx.x;
  double scale = (k == 0) ? 0.0625 : 0.08838834764831844;  // sqrt(1/256), sqrt(2/256)
  double val = cos(3.14159265358979323846 * ((double)h + 0.5) * (double)k / 256.0) * scale;
  f16 vh = (f16)((float)val);
  Cf[frag_off(k, h)] = vh;   // row k, col h
  CTf[frag_off(h, k)] = vh;  // row h, col k
  if (k < 128) {
    float tb = t[k];
    float sg = expf(-0.69314718055994531f * (1.0f - tb) + 2.99573227355399099f * tb);
    float tau = 0.5f * sg * sg;
    float f = 3.14159265358979f * (float)h / 256.0f;
    g[k * NSZ + h] = expf(-f * f * tau);
  }
}

#define TBL_FRAG(Tf, tile, q, lane) (*(const f16x8*)&(Tf)[((((tile) * 16 + (q)) << 6) + (lane)) << 3])

// GEMM with A from LDS (rows rbase band), B from frag table (tiles tB0,tB0+1).
__device__ __forceinline__ void gemm_AL_BT(const f16* L, const f16* __restrict__ Tf,
                                           int rbase, int tB0, int lane,
                                           f32x16 (&acc)[4][2]) {
  int l31 = lane & 31, kh = (lane >> 5) * 8;
#pragma unroll 4
  for (int q = 0; q < 16; ++q) {
    f16x8 a[4], b[2];
#pragma unroll
    for (int fi = 0; fi < 4; ++fi)
      a[fi] = *(const f16x8*)&L[sw(rbase + fi * 32 + l31, q * 16 + kh)];
#pragma unroll
    for (int fj = 0; fj < 2; ++fj)
      b[fj] = TBL_FRAG(Tf, tB0 + fj, q, lane);
#pragma unroll
    for (int fi = 0; fi < 4; ++fi)
#pragma unroll
      for (int fj = 0; fj < 2; ++fj)
        acc[fi][fj] = __builtin_amdgcn_mfma_f32_32x32x16_f16(a[fi], b[fj], acc[fi][fj], 0, 0, 0);
  }
}

// Transposed writeback to LDS: L[c][r] = D[r][c].
// D layout (32x32): col = lane&31, row = (v&3) + 8*(v>>2) + 4*(lane>>5).
__device__ __forceinline__ void writeT(f16* L, int rbase, int cbase, int lane,
                                       const f32x16 (&acc)[4][2]) {
  int l31 = lane & 31, hi4 = (lane >> 5) * 4;
#pragma unroll
  for (int fi = 0; fi < 4; ++fi)
#pragma unroll
    for (int fj = 0; fj < 2; ++fj) {
      int crow = cbase + fj * 32 + l31;
#pragma unroll
      for (int v2 = 0; v2 < 4; ++v2) {
        int colbase = rbase + fi * 32 + v2 * 8 + hi4;
        f16x4 hv;
        hv[0] = (f16)acc[fi][fj][v2 * 4 + 0];
        hv[1] = (f16)acc[fi][fj][v2 * 4 + 1];
        hv[2] = (f16)acc[fi][fj][v2 * 4 + 2];
        hv[3] = (f16)acc[fi][fj][v2 * 4 + 3];
        *(f16x4*)&L[sw(crow, colbase)] = hv;
      }
    }
}

__global__ __launch_bounds__(512, 2) void fused_kernel(
    const float* __restrict__ x, float* __restrict__ out,
    const f16* __restrict__ Cf, const f16* __restrict__ CTf,
    const float* __restrict__ g) {
  __shared__ f16 L[NSZ * NSZ];  // 128 KiB

  const int img = blockIdx.x;
  const int b = img / 3;
  const float* X = x + (size_t)img * 65536;
  float* Y = out + (size_t)img * 65536;

  const int t = threadIdx.x;
  const int lane = t & 63;
  const int wave = t >> 6;
  const int r0 = (wave >> 2) * 128;
  const int c0 = (wave & 3) * 64;
  const int l31 = lane & 31;
  const int kh = (lane >> 5) * 8;
  const int hi4 = (lane >> 5) * 4;
  const int tB0 = c0 >> 5;

  f32x16 acc[4][2];
  const f32x16 zz = {0.f, 0.f, 0.f, 0.f, 0.f, 0.f, 0.f, 0.f,
                     0.f, 0.f, 0.f, 0.f, 0.f, 0.f, 0.f, 0.f};
#pragma unroll
  for (int fi = 0; fi < 4; ++fi)
#pragma unroll
    for (int fj = 0; fj < 2; ++fj) acc[fi][fj] = zz;

  // ---- S1 pipelined: X fp32 -> LDS f16 in 4 column-chunks, overlapped with S1 MFMA.
  // Thread mapping per chunk: row = t>>1, cols [cw*64 + (t&1)*32, +32) = 8 float4.
  const int xr_row = t >> 1;
  const int xr_half = (t & 1) * 32;
  float4 xa[2][8];
#pragma unroll
  for (int s = 0; s < 8; ++s) xa[0][s] = *(const float4*)&X[xr_row * NSZ + xr_half + s * 4];

#pragma unroll
  for (int cw = 0; cw < 4; ++cw) {
    int cb = cw & 1;
    // prefetch next chunk
    if (cw < 3) {
#pragma unroll
      for (int s = 0; s < 8; ++s)
        xa[cb ^ 1][s] = *(const float4*)&X[xr_row * NSZ + (cw + 1) * 64 + xr_half + s * 4];
    }
    // convert + LDS write current chunk
#pragma unroll
    for (int g8 = 0; g8 < 4; ++g8) {
      float4 a0 = xa[cb][g8 * 2], a1 = xa[cb][g8 * 2 + 1];
      f16x8 v;
      v[0] = (f16)a0.x; v[1] = (f16)a0.y; v[2] = (f16)a0.z; v[3] = (f16)a0.w;
      v[4] = (f16)a1.x; v[5] = (f16)a1.y; v[6] = (f16)a1.z; v[7] = (f16)a1.w;
      *(f16x8*)&L[sw(xr_row, cw * 64 + xr_half + g8 * 8)] = v;
    }
    __syncthreads();
    // S1 partial compute on chunk cw: q = cw*4 .. cw*4+3
#pragma unroll
    for (int q4 = 0; q4 < 4; ++q4) {
      int q = cw * 4 + q4;
      f16x8 a[4], bfr[2];
#pragma unroll
      for (int fi = 0; fi < 4; ++fi)
        a[fi] = *(const f16x8*)&L[sw(r0 + fi * 32 + l31, q * 16 + kh)];
#pragma unroll
      for (int fj = 0; fj < 2; ++fj)
        bfr[fj] = TBL_FRAG(Cf, tB0 + fj, q, lane);
#pragma unroll
      for (int fi = 0; fi < 4; ++fi)
#pragma unroll
        for (int fj = 0; fj < 2; ++fj)
          acc[fi][fj] = __builtin_amdgcn_mfma_f32_32x32x16_f16(a[fi], bfr[fj], acc[fi][fj], 0, 0, 0);
    }
    __syncthreads();  // chunk consumed by all waves before anything else lands
  }
  // S1 done: D[h][n]; writeT -> L1[n][h]
  writeT(L, r0, c0, lane, acc);
  __syncthreads();

  // ---- S2: D[n][k'] = sum_h L1[n,h] * C[k',h]  (B = Cf rows k')
#pragma unroll
  for (int fi = 0; fi < 4; ++fi)
#pragma unroll
    for (int fj = 0; fj < 2; ++fj) acc[fi][fj] = zz;
  gemm_AL_BT(L, Cf, r0, tB0, lane, acc);
  // exact scale: s = mask(g_k' * g_n) * 0.999 + 0.001  (cols = k', rows = n)
  {
    const float* gb = g + b * NSZ;
#pragma unroll
    for (int fj = 0; fj < 2; ++fj) {
      float gk = gb[c0 + fj * 32 + l31];
#pragma unroll
      for (int fi = 0; fi < 4; ++fi) {
#pragma unroll
        for (int v2 = 0; v2 < 4; ++v2) {
          float4 gn = *(const float4*)&gb[r0 + fi * 32 + v2 * 8 + hi4];
          float gnv[4] = {gn.x, gn.y, gn.z, gn.w};
#pragma unroll
          for (int e = 0; e < 4; ++e) {
            float fade = gk * gnv[e];
            float s = ((fade < 0.01f) ? 0.f : fade) * 0.999f + 0.001f;
            acc[fi][fj][v2 * 4 + e] *= s;
          }
        }
      }
    }
  }
  __syncthreads();
  writeT(L, r0, c0, lane, acc);  // L2[k'][n]
  __syncthreads();

  // ---- S3: D[k][w] = sum_n L2[k,n] * C[n,w]  (B = CTf rows w)
#pragma unroll
  for (int fi = 0; fi < 4; ++fi)
#pragma unroll
    for (int fj = 0; fj < 2; ++fj) acc[fi][fj] = zz;
  gemm_AL_BT(L, CTf, r0, tB0, lane, acc);
  __syncthreads();
  writeT(L, r0, c0, lane, acc);  // L3[w][k]
  __syncthreads();

  // ---- S4: Y[h][w] = sum_k C[k,h] * Q[k,w]   (A = CTf rows h, B = LDS L3 rows w)
#pragma unroll
  for (int fi = 0; fi < 4; ++fi)
#pragma unroll
    for (int fj = 0; fj < 2; ++fj) acc[fi][fj] = zz;
  {
    int tA0 = r0 >> 5;
#pragma unroll 4
    for (int q = 0; q < 16; ++q) {
      f16x8 a[4], bfr[2];
#pragma unroll
      for (int fi = 0; fi < 4; ++fi)
        a[fi] = TBL_FRAG(CTf, tA0 + fi, q, lane);
#pragma unroll
      for (int fj = 0; fj < 2; ++fj)
        bfr[fj] = *(const f16x8*)&L[sw(c0 + fj * 32 + l31, q * 16 + kh)];
#pragma unroll
      for (int fi = 0; fi < 4; ++fi)
#pragma unroll
        for (int fj = 0; fj < 2; ++fj)
          acc[fi][fj] = __builtin_amdgcn_mfma_f32_32x32x16_f16(a[fi], bfr[fj], acc[fi][fj], 0, 0, 0);
    }
  }
  // store: D rows = h, cols = w -> coalesced 128B per 32-lane group
#pragma unroll
  for (int fi = 0; fi < 4; ++fi)
#pragma unroll
    for (int fj = 0; fj < 2; ++fj) {
      int w = c0 + fj * 32 + l31;
#pragma unroll
      for (int v2 = 0; v2 < 4; ++v2) {
#pragma unroll
        for (int e = 0; e < 4; ++e) {
          int h = r0 + fi * 32 + v2 * 8 + hi4 + e;
          Y[h * NSZ + w] = acc[fi][fj][v2 * 4 + e];
        }
      }
    }
}

extern "C" void kernel_launch(void* const* d_in, const int* in_sizes, int n_in,
                              void* d_out, int out_size, void* d_ws, size_t ws_size,
                              hipStream_t stream) {
  const float* x = (const float*)d_in[0];
  const float* t = (const float*)d_in[1];
  float* out = (float*)d_out;

  char* ws = (char*)d_ws;
  float* g = (float*)ws;           // 128*256*4 = 131072 B
  f16* Cf = (f16*)(ws + 131072);   // 131072 B (frag layout)
  f16* CTf = (f16*)(ws + 262144);  // 131072 B (frag layout)

  prep_kernel<<<256, 256, 0, stream>>>(Cf, CTf, g, t);
  fused_kernel<<<NIMG, 512, 0, stream>>>(x, out, Cf, CTf, g);
}